// Round 6
// baseline (217.908 us; speedup 1.0000x reference)
//
#include <hip/hip_runtime.h>
#include <hip/hip_bf16.h>

#define D_DIM   128
#define MT      64        // node rows per block-iteration (3125 tiles exactly)
#define NBLOCKS 512       // persistent: 2 blocks/CU x 256 CUs
#define NTHR    512

typedef __attribute__((ext_vector_type(8))) short bf16x8;
typedef __attribute__((ext_vector_type(4))) float f32x4;

__device__ __forceinline__ unsigned short f2bf(float f) {
    return __builtin_bit_cast(unsigned short, __float2bfloat16(f));
}

// XOR-swizzled offset (in shorts) into a [rows][128] bf16 LDS tile.
// 16B chunks permuted per row: conflict-free ds_read_b128, zero padding.
__device__ __forceinline__ int sw_off(int row, int col) {
    return row * 128 + ((((col >> 3) ^ (row & 15)) << 3) | (col & 7));
}

// stage a 128x128 fp32 matrix into swizzled bf16 LDS; coalesced global reads
__device__ __forceinline__ void stage_w(const float* __restrict__ w,
                                        unsigned short* __restrict__ sW, int t) {
    #pragma unroll
    for (int i = 0; i < 8; ++i) {                 // 4096 float4 / 512 threads
        const int idx4 = i * NTHR + t;
        const float4 v = ((const float4*)w)[idx4];
        const int row = idx4 >> 5;                // 32 float4 per row
        const int c4  = (idx4 & 31) * 4;
        ushort4 b;
        b.x = f2bf(v.x); b.y = f2bf(v.y); b.z = f2bf(v.z); b.w = f2bf(v.w);
        *(ushort4*)&sW[sw_off(row, c4)] = b;
    }
}

__global__ __launch_bounds__(NTHR, 4)
void ctx_encoder(const int* __restrict__ nodes,
                 const float* __restrict__ c2e,
                 const float* __restrict__ w1,
                 const float* __restrict__ b1,
                 const float* __restrict__ w2,
                 const float* __restrict__ b2,
                 float* __restrict__ out,
                 int N) {
    __shared__ unsigned short sW1[D_DIM * 128];   // 32 KB
    __shared__ unsigned short sW2[D_DIM * 128];   // 32 KB
    __shared__ unsigned short sX [MT    * 128];   // 16 KB shared A/h buffer -> 80 KB

    const int t    = threadIdx.x;
    const int lane = t & 63;
    const int wave = t >> 6;       // 0..7
    const int pair = wave >> 1;    // m-tile 0..3 (16 rows)
    const int half = wave & 1;     // ct-group
    const int cl   = lane & 15;
    const int quad = lane >> 4;

    // gather role: thread t fetches contiguous 16B slices of row (t>>3)
    const int grow0 = t >> 3;      // row within tile, 0..63
    const int gc    = t & 7;       // 16B chunk position

    stage_w(w1, sW1, t);
    stage_w(w2, sW2, t);

    float bias1[4], bias2[4];
    #pragma unroll
    for (int c = 0; c < 4; ++c) {
        const int j = (half * 4 + c) * 16 + cl;
        bias1[c] = b1[j];
        bias2[c] = b2[j];
    }

    const int nTiles = (N + MT - 1) / MT;
    const int lastT  = nTiles - 1;

    // clamped node-index load for tile tt (dupes at tail are harmless)
    auto loadIdx = [&](int tt) -> int {
        tt = tt < lastT ? tt : lastT;
        int r = tt * MT + grow0;
        r = r < N ? r : N - 1;
        return nodes[r];
    };
    auto gather = [&](int idx, float4* g) {
        const float* rp = c2e + (size_t)idx * D_DIM + gc * 4;
        #pragma unroll
        for (int i = 0; i < 4; ++i)
            g[i] = *(const float4*)(rp + i * 32);   // 8x128B contiguous runs/instr
    };

    int tl = blockIdx.x;
    float4 g0[4], g1[4];

    // ---- prologue: two tiles of gather in flight, indices two more ahead ----
    int idxA = loadIdx(tl);
    gather(idxA, g0);
    int idxB = loadIdx(tl + NBLOCKS);
    gather(idxB, g1);
    int idxN0 = loadIdx(tl + 2 * NBLOCKS);   // next refill for g0
    int idxN1 = loadIdx(tl + 3 * NBLOCKS);   // next refill for g1

    __syncthreads();   // weights staged

    // one tile's worth of work; refills g with tile (tcur + 2*NBLOCKS)
    auto body = [&](int tcur, float4* g, int& idxRef) {
        // s1: gathered rows -> bf16 -> sX (swizzled)
        #pragma unroll
        for (int i = 0; i < 4; ++i) {
            ushort4 b;
            b.x = f2bf(g[i].x); b.y = f2bf(g[i].y);
            b.z = f2bf(g[i].z); b.w = f2bf(g[i].w);
            *(ushort4*)&sX[sw_off(grow0, gc * 4 + i * 32)] = b;
        }
        __syncthreads();   // B1: sX(A) ready

        // s2: A-fragments from LDS
        bf16x8 aF[4];
        #pragma unroll
        for (int ks = 0; ks < 4; ++ks)
            aF[ks] = *(const bf16x8*)&sX[sw_off(pair * 16 + cl, ks * 32 + quad * 8)];

        // s3: refill gather (distance 2) + advance index pipeline
        gather(idxRef, g);
        idxRef = loadIdx(tcur + 4 * NBLOCKS);
        __syncthreads();   // B2: aF reads done; sX reusable for h

        // s4: layer 1 -> h into sX
        #pragma unroll
        for (int c = 0; c < 4; ++c) {
            const int ct = half * 4 + c;
            bf16x8 bF[4];
            #pragma unroll
            for (int ks = 0; ks < 4; ++ks)
                bF[ks] = *(const bf16x8*)&sW1[sw_off(ct * 16 + cl, ks * 32 + quad * 8)];
            f32x4 acc = {0.f, 0.f, 0.f, 0.f};
            #pragma unroll
            for (int ks = 0; ks < 4; ++ks)
                acc = __builtin_amdgcn_mfma_f32_16x16x32_bf16(aF[ks], bF[ks], acc, 0, 0, 0);
            const int j = ct * 16 + cl;
            #pragma unroll
            for (int r = 0; r < 4; ++r) {
                float h = acc[r] + bias1[c];
                h = h > 0.f ? h : 0.f;
                sX[sw_off(pair * 16 + quad * 4 + r, j)] = f2bf(h);
            }
        }
        __syncthreads();   // B3: sX(h) ready

        // s5: h-fragments
        bf16x8 hF[4];
        #pragma unroll
        for (int ks = 0; ks < 4; ++ks)
            hF[ks] = *(const bf16x8*)&sX[sw_off(pair * 16 + cl, ks * 32 + quad * 8)];
        __syncthreads();   // B4: hF reads done; sX free for next gather

        // s6: layer 2 + nontemporal store (one-shot stream, keep L2/L3 for table)
        const size_t obase = (size_t)tcur * MT;
        #pragma unroll
        for (int c = 0; c < 4; ++c) {
            const int ct = half * 4 + c;
            bf16x8 bF[4];
            #pragma unroll
            for (int ks = 0; ks < 4; ++ks)
                bF[ks] = *(const bf16x8*)&sW2[sw_off(ct * 16 + cl, ks * 32 + quad * 8)];
            f32x4 acc = {0.f, 0.f, 0.f, 0.f};
            #pragma unroll
            for (int ks = 0; ks < 4; ++ks)
                acc = __builtin_amdgcn_mfma_f32_16x16x32_bf16(hF[ks], bF[ks], acc, 0, 0, 0);
            const int j = ct * 16 + cl;
            #pragma unroll
            for (int r = 0; r < 4; ++r) {
                float o = acc[r] + bias2[c];
                o = o > 0.f ? o : 0.f;
                const long grow = (long)(obase + pair * 16 + quad * 4 + r);
                if (grow < N)
                    __builtin_nontemporal_store(o, &out[(size_t)grow * D_DIM + j]);
            }
        }
    };

    for (; tl < nTiles; tl += 2 * NBLOCKS) {
        body(tl, g0, idxN0);                  // consumes g0, refills with tl+2NB
        if (tl + NBLOCKS < nTiles)            // block-uniform condition
            body(tl + NBLOCKS, g1, idxN1);    // consumes g1, refills with tl+3NB
    }
}

extern "C" void kernel_launch(void* const* d_in, const int* in_sizes, int n_in,
                              void* d_out, int out_size, void* d_ws, size_t ws_size,
                              hipStream_t stream) {
    const int*   nodes = (const int*)d_in[0];
    const float* c2e   = (const float*)d_in[1];
    const float* w1    = (const float*)d_in[2];
    const float* b1    = (const float*)d_in[3];
    const float* w2    = (const float*)d_in[4];
    const float* b2    = (const float*)d_in[5];
    float* out = (float*)d_out;
    const int N = in_sizes[0];

    ctx_encoder<<<dim3(NBLOCKS), dim3(NTHR), 0, stream>>>(nodes, c2e, w1, b1, w2, b2, out, N);
}

// Round 7
// 203.973 us; speedup vs baseline: 1.0683x; 1.0683x over previous
//
#include <hip/hip_runtime.h>
#include <hip/hip_bf16.h>

#define D_DIM   128
#define MT      64        // node rows per block-iteration (3125 tiles exactly)
#define NBLOCKS 512       // persistent: 2 blocks/CU x 256 CUs
#define NTHR    512

typedef __attribute__((ext_vector_type(8))) short bf16x8;
typedef __attribute__((ext_vector_type(4))) float f32x4;

__device__ __forceinline__ unsigned short f2bf(float f) {
    return __builtin_bit_cast(unsigned short, __float2bfloat16(f));
}

// XOR-swizzled offset (in shorts) into a [rows][128] bf16 LDS tile.
// 16B chunks permuted per row: conflict-free ds_read_b128, zero padding.
__device__ __forceinline__ int sw_off(int row, int col) {
    return row * 128 + ((((col >> 3) ^ (row & 15)) << 3) | (col & 7));
}

// stage a 128x128 fp32 matrix into swizzled bf16 LDS; coalesced global reads
__device__ __forceinline__ void stage_w(const float* __restrict__ w,
                                        unsigned short* __restrict__ sW, int t) {
    #pragma unroll
    for (int i = 0; i < 8; ++i) {                 // 4096 float4 / 512 threads
        const int idx4 = i * NTHR + t;
        const float4 v = ((const float4*)w)[idx4];
        const int row = idx4 >> 5;                // 32 float4 per row
        const int c4  = (idx4 & 31) * 4;
        ushort4 b;
        b.x = f2bf(v.x); b.y = f2bf(v.y); b.z = f2bf(v.z); b.w = f2bf(v.w);
        *(ushort4*)&sW[sw_off(row, c4)] = b;
    }
}

__global__ __launch_bounds__(NTHR, 4)
void ctx_encoder(const int* __restrict__ nodes,
                 const float* __restrict__ c2e,
                 const float* __restrict__ w1,
                 const float* __restrict__ b1,
                 const float* __restrict__ w2,
                 const float* __restrict__ b2,
                 float* __restrict__ out,
                 int N) {
    __shared__ unsigned short sW1[D_DIM * 128];   // 32 KB
    __shared__ unsigned short sW2[D_DIM * 128];   // 32 KB
    __shared__ unsigned short sX [MT    * 128];   // 16 KB shared A/h buffer -> 80 KB

    const int t    = threadIdx.x;
    const int lane = t & 63;
    const int wave = t >> 6;       // 0..7
    const int pair = wave >> 1;    // m-tile 0..3 (16 node rows)
    const int half = wave & 1;     // ct-group
    const int cl   = lane & 15;
    const int quad = lane >> 4;

    // gather role: thread t fetches contiguous 16B slices of row (t>>3)
    const int grow0 = t >> 3;      // row within tile, 0..63
    const int gc    = t & 7;       // 16B chunk position (8 lanes = 128B runs)

    stage_w(w1, sW1, t);
    stage_w(w2, sW2, t);

    // biases, vectorized per (c, quad): j = ct*16 + quad*4 + r
    float4 bias1[4], bias2[4];
    #pragma unroll
    for (int c = 0; c < 4; ++c) {
        const int ct = half * 4 + c;
        bias1[c] = ((const float4*)b1)[ct * 4 + quad];
        bias2[c] = ((const float4*)b2)[ct * 4 + quad];
    }

    const int nTiles = (N + MT - 1) / MT;
    const int lastT  = nTiles - 1;

    auto loadIdx = [&](int tt) -> int {
        tt = tt < lastT ? tt : lastT;
        int r = tt * MT + grow0;
        r = r < N ? r : N - 1;
        return nodes[r];
    };
    auto gather = [&](int idx, float4* g) {
        const float* rp = c2e + (size_t)idx * D_DIM + gc * 4;
        #pragma unroll
        for (int i = 0; i < 4; ++i)
            g[i] = *(const float4*)(rp + i * 32);   // 8x128B contiguous runs/instr
    };

    int tl = blockIdx.x;
    float4 g0[4], g1[4];

    // ---- prologue: two tiles of gather in flight ----
    int idxA = loadIdx(tl);
    gather(idxA, g0);
    int idxB = loadIdx(tl + NBLOCKS);
    gather(idxB, g1);
    int idxN0 = loadIdx(tl + 2 * NBLOCKS);
    int idxN1 = loadIdx(tl + 3 * NBLOCKS);

    __syncthreads();   // weights staged

    auto body = [&](int tcur, float4* g, int& idxRef) {
        // s1: gathered rows -> bf16 -> sX (swizzled)
        #pragma unroll
        for (int i = 0; i < 4; ++i) {
            ushort4 b;
            b.x = f2bf(g[i].x); b.y = f2bf(g[i].y);
            b.z = f2bf(g[i].z); b.w = f2bf(g[i].w);
            *(ushort4*)&sX[sw_off(grow0, gc * 4 + i * 32)] = b;
        }
        __syncthreads();   // B1: sX(A) ready

        // s2: x-fragments from LDS (lane: x[node=cl][k=quad*8..+7])
        bf16x8 xF[4];
        #pragma unroll
        for (int ks = 0; ks < 4; ++ks)
            xF[ks] = *(const bf16x8*)&sX[sw_off(pair * 16 + cl, ks * 32 + quad * 8)];

        // s3: refill gather (distance 2) + advance index pipeline
        gather(idxRef, g);
        idxRef = loadIdx(tcur + 4 * NBLOCKS);
        __syncthreads();   // B2: xF reads done; sX reusable for h

        // s4: layer 1, operand-swapped: acc = W1tile x X^T  (lane reg axis = j)
        #pragma unroll
        for (int c = 0; c < 4; ++c) {
            const int ct = half * 4 + c;
            bf16x8 wF[4];
            #pragma unroll
            for (int ks = 0; ks < 4; ++ks)
                wF[ks] = *(const bf16x8*)&sW1[sw_off(ct * 16 + cl, ks * 32 + quad * 8)];
            f32x4 acc = {0.f, 0.f, 0.f, 0.f};
            #pragma unroll
            for (int ks = 0; ks < 4; ++ks)
                acc = __builtin_amdgcn_mfma_f32_16x16x32_bf16(wF[ks], xF[ks], acc, 0, 0, 0);
            // lane holds h[node=cl][j = ct*16 + quad*4 + r], r=0..3 -> ushort4
            ushort4 hw;
            float h0 = acc[0] + bias1[c].x;  h0 = h0 > 0.f ? h0 : 0.f;  hw.x = f2bf(h0);
            float h1 = acc[1] + bias1[c].y;  h1 = h1 > 0.f ? h1 : 0.f;  hw.y = f2bf(h1);
            float h2 = acc[2] + bias1[c].z;  h2 = h2 > 0.f ? h2 : 0.f;  hw.z = f2bf(h2);
            float h3 = acc[3] + bias1[c].w;  h3 = h3 > 0.f ? h3 : 0.f;  hw.w = f2bf(h3);
            *(ushort4*)&sX[sw_off(pair * 16 + cl, ct * 16 + quad * 4)] = hw;
        }
        __syncthreads();   // B3: sX(h) ready

        // s5: h-fragments
        bf16x8 hF[4];
        #pragma unroll
        for (int ks = 0; ks < 4; ++ks)
            hF[ks] = *(const bf16x8*)&sX[sw_off(pair * 16 + cl, ks * 32 + quad * 8)];
        __syncthreads();   // B4: hF reads done; sX free for next gather

        // s6: layer 2, operand-swapped + float4 stores
        const size_t orow = (size_t)tcur * MT + pair * 16 + cl;
        const bool rowOk = orow < (size_t)N;
        #pragma unroll
        for (int c = 0; c < 4; ++c) {
            const int ct = half * 4 + c;
            bf16x8 wF[4];
            #pragma unroll
            for (int ks = 0; ks < 4; ++ks)
                wF[ks] = *(const bf16x8*)&sW2[sw_off(ct * 16 + cl, ks * 32 + quad * 8)];
            f32x4 acc = {0.f, 0.f, 0.f, 0.f};
            #pragma unroll
            for (int ks = 0; ks < 4; ++ks)
                acc = __builtin_amdgcn_mfma_f32_16x16x32_bf16(wF[ks], hF[ks], acc, 0, 0, 0);
            float4 o;
            o.x = acc[0] + bias2[c].x;  o.x = o.x > 0.f ? o.x : 0.f;
            o.y = acc[1] + bias2[c].y;  o.y = o.y > 0.f ? o.y : 0.f;
            o.z = acc[2] + bias2[c].z;  o.z = o.z > 0.f ? o.z : 0.f;
            o.w = acc[3] + bias2[c].w;  o.w = o.w > 0.f ? o.w : 0.f;
            if (rowOk)
                *(float4*)&out[orow * D_DIM + ct * 16 + quad * 4] = o;
        }
    };

    for (; tl < nTiles; tl += 2 * NBLOCKS) {
        body(tl, g0, idxN0);
        if (tl + NBLOCKS < nTiles)            // block-uniform condition
            body(tl + NBLOCKS, g1, idxN1);
    }
}

extern "C" void kernel_launch(void* const* d_in, const int* in_sizes, int n_in,
                              void* d_out, int out_size, void* d_ws, size_t ws_size,
                              hipStream_t stream) {
    const int*   nodes = (const int*)d_in[0];
    const float* c2e   = (const float*)d_in[1];
    const float* w1    = (const float*)d_in[2];
    const float* b1    = (const float*)d_in[3];
    const float* w2    = (const float*)d_in[4];
    const float* b2    = (const float*)d_in[5];
    float* out = (float*)d_out;
    const int N = in_sizes[0];

    ctx_encoder<<<dim3(NBLOCKS), dim3(NTHR), 0, stream>>>(nodes, c2e, w1, b1, w2, b2, out, N);
}

// Round 8
// 203.688 us; speedup vs baseline: 1.0698x; 1.0014x over previous
//
#include <hip/hip_runtime.h>
#include <hip/hip_bf16.h>

#define D_DIM   128
#define MT      64        // node rows per block-iteration (3125 tiles exactly)
#define NBLOCKS 512       // persistent: 2 blocks/CU x 256 CUs
#define NTHR    512

typedef __attribute__((ext_vector_type(8))) short bf16x8;
typedef __attribute__((ext_vector_type(4))) float f32x4;

__device__ __forceinline__ unsigned short f2bf(float f) {
    return __builtin_bit_cast(unsigned short, __float2bfloat16(f));
}

// XOR-swizzled offset (in shorts) into a [rows][128] bf16 LDS tile.
// 16B chunks permuted per row: conflict-free ds_read_b128, zero padding.
__device__ __forceinline__ int sw_off(int row, int col) {
    return row * 128 + ((((col >> 3) ^ (row & 15)) << 3) | (col & 7));
}

// stage a 128x128 fp32 matrix into swizzled bf16 LDS; coalesced global reads
__device__ __forceinline__ void stage_w(const float* __restrict__ w,
                                        unsigned short* __restrict__ sW, int t) {
    #pragma unroll
    for (int i = 0; i < 8; ++i) {                 // 4096 float4 / 512 threads
        const int idx4 = i * NTHR + t;
        const float4 v = ((const float4*)w)[idx4];
        const int row = idx4 >> 5;                // 32 float4 per row
        const int c4  = (idx4 & 31) * 4;
        ushort4 b;
        b.x = f2bf(v.x); b.y = f2bf(v.y); b.z = f2bf(v.z); b.w = f2bf(v.w);
        *(ushort4*)&sW[sw_off(row, c4)] = b;
    }
}

// gather one embedding row slice into 4 named float4 registers (NOT an array:
// addressable locals get demoted to scratch -> HBM spill traffic, see R6/R7)
#define GATHER(IDX, G0, G1, G2, G3)                                    \
    {                                                                  \
        const float* rp_ = c2e + (size_t)(IDX) * D_DIM + gc * 4;       \
        G0 = *(const float4*)(rp_);                                    \
        G1 = *(const float4*)(rp_ + 32);                               \
        G2 = *(const float4*)(rp_ + 64);                               \
        G3 = *(const float4*)(rp_ + 96);                               \
    }

// one tile: stage gathered regs -> LDS, layer1, layer2, store; refill G with
// tile (TCUR + 2*NBLOCKS) and advance its index register.
#define BODY(TCUR, G0, G1, G2, G3, IDXREF)                                     \
    {                                                                          \
        /* s1: gathered rows -> bf16 -> sX (swizzled) */                       \
        {                                                                      \
            ushort4 b_;                                                        \
            b_.x = f2bf(G0.x); b_.y = f2bf(G0.y);                              \
            b_.z = f2bf(G0.z); b_.w = f2bf(G0.w);                              \
            *(ushort4*)&sX[sw_off(grow0, gc * 4)] = b_;                        \
            b_.x = f2bf(G1.x); b_.y = f2bf(G1.y);                              \
            b_.z = f2bf(G1.z); b_.w = f2bf(G1.w);                              \
            *(ushort4*)&sX[sw_off(grow0, gc * 4 + 32)] = b_;                   \
            b_.x = f2bf(G2.x); b_.y = f2bf(G2.y);                              \
            b_.z = f2bf(G2.z); b_.w = f2bf(G2.w);                              \
            *(ushort4*)&sX[sw_off(grow0, gc * 4 + 64)] = b_;                   \
            b_.x = f2bf(G3.x); b_.y = f2bf(G3.y);                              \
            b_.z = f2bf(G3.z); b_.w = f2bf(G3.w);                              \
            *(ushort4*)&sX[sw_off(grow0, gc * 4 + 96)] = b_;                   \
        }                                                                      \
        __syncthreads(); /* B1: sX(A) ready */                                 \
        /* s2: x-fragments from LDS */                                         \
        bf16x8 xF0 = *(const bf16x8*)&sX[sw_off(pair * 16 + cl, quad * 8)];    \
        bf16x8 xF1 = *(const bf16x8*)&sX[sw_off(pair * 16 + cl, 32 + quad * 8)];\
        bf16x8 xF2 = *(const bf16x8*)&sX[sw_off(pair * 16 + cl, 64 + quad * 8)];\
        bf16x8 xF3 = *(const bf16x8*)&sX[sw_off(pair * 16 + cl, 96 + quad * 8)];\
        /* s3: refill gather (distance 2) + advance index pipeline */          \
        GATHER(IDXREF, G0, G1, G2, G3);                                        \
        IDXREF = loadIdx((TCUR) + 4 * NBLOCKS);                                \
        __syncthreads(); /* B2: xF reads done; sX reusable for h */            \
        /* s4: layer 1, operand-swapped: lane reg axis = feature j */          \
        _Pragma("unroll")                                                      \
        for (int c = 0; c < 4; ++c) {                                          \
            const int ct = half * 4 + c;                                       \
            const int wr = sw_off(ct * 16 + cl, quad * 8);                     \
            bf16x8 w0 = *(const bf16x8*)&sW1[wr];                              \
            bf16x8 w1_ = *(const bf16x8*)&sW1[sw_off(ct * 16 + cl, 32 + quad * 8)];\
            bf16x8 w2_ = *(const bf16x8*)&sW1[sw_off(ct * 16 + cl, 64 + quad * 8)];\
            bf16x8 w3_ = *(const bf16x8*)&sW1[sw_off(ct * 16 + cl, 96 + quad * 8)];\
            f32x4 acc = {0.f, 0.f, 0.f, 0.f};                                  \
            acc = __builtin_amdgcn_mfma_f32_16x16x32_bf16(w0, xF0, acc, 0, 0, 0);\
            acc = __builtin_amdgcn_mfma_f32_16x16x32_bf16(w1_, xF1, acc, 0, 0, 0);\
            acc = __builtin_amdgcn_mfma_f32_16x16x32_bf16(w2_, xF2, acc, 0, 0, 0);\
            acc = __builtin_amdgcn_mfma_f32_16x16x32_bf16(w3_, xF3, acc, 0, 0, 0);\
            ushort4 hw;                                                        \
            float h0 = acc[0] + bias1[c].x;  h0 = h0 > 0.f ? h0 : 0.f;         \
            float h1 = acc[1] + bias1[c].y;  h1 = h1 > 0.f ? h1 : 0.f;         \
            float h2 = acc[2] + bias1[c].z;  h2 = h2 > 0.f ? h2 : 0.f;         \
            float h3 = acc[3] + bias1[c].w;  h3 = h3 > 0.f ? h3 : 0.f;         \
            hw.x = f2bf(h0); hw.y = f2bf(h1); hw.z = f2bf(h2); hw.w = f2bf(h3);\
            *(ushort4*)&sX[sw_off(pair * 16 + cl, ct * 16 + quad * 4)] = hw;   \
        }                                                                      \
        __syncthreads(); /* B3: sX(h) ready */                                 \
        /* s5: h-fragments */                                                  \
        bf16x8 hF0 = *(const bf16x8*)&sX[sw_off(pair * 16 + cl, quad * 8)];    \
        bf16x8 hF1 = *(const bf16x8*)&sX[sw_off(pair * 16 + cl, 32 + quad * 8)];\
        bf16x8 hF2 = *(const bf16x8*)&sX[sw_off(pair * 16 + cl, 64 + quad * 8)];\
        bf16x8 hF3 = *(const bf16x8*)&sX[sw_off(pair * 16 + cl, 96 + quad * 8)];\
        __syncthreads(); /* B4: hF reads done; sX free for next gather */      \
        /* s6: layer 2, operand-swapped + float4 stores */                     \
        {                                                                      \
            const size_t orow = (size_t)(TCUR) * MT + pair * 16 + cl;          \
            const bool rowOk = orow < (size_t)N;                               \
            _Pragma("unroll")                                                  \
            for (int c = 0; c < 4; ++c) {                                      \
                const int ct = half * 4 + c;                                   \
                bf16x8 w0 = *(const bf16x8*)&sW2[sw_off(ct * 16 + cl, quad * 8)];\
                bf16x8 w1_ = *(const bf16x8*)&sW2[sw_off(ct * 16 + cl, 32 + quad * 8)];\
                bf16x8 w2_ = *(const bf16x8*)&sW2[sw_off(ct * 16 + cl, 64 + quad * 8)];\
                bf16x8 w3_ = *(const bf16x8*)&sW2[sw_off(ct * 16 + cl, 96 + quad * 8)];\
                f32x4 acc = {0.f, 0.f, 0.f, 0.f};                              \
                acc = __builtin_amdgcn_mfma_f32_16x16x32_bf16(w0, hF0, acc, 0, 0, 0);\
                acc = __builtin_amdgcn_mfma_f32_16x16x32_bf16(w1_, hF1, acc, 0, 0, 0);\
                acc = __builtin_amdgcn_mfma_f32_16x16x32_bf16(w2_, hF2, acc, 0, 0, 0);\
                acc = __builtin_amdgcn_mfma_f32_16x16x32_bf16(w3_, hF3, acc, 0, 0, 0);\
                float4 o;                                                      \
                o.x = acc[0] + bias2[c].x;  o.x = o.x > 0.f ? o.x : 0.f;       \
                o.y = acc[1] + bias2[c].y;  o.y = o.y > 0.f ? o.y : 0.f;       \
                o.z = acc[2] + bias2[c].z;  o.z = o.z > 0.f ? o.z : 0.f;       \
                o.w = acc[3] + bias2[c].w;  o.w = o.w > 0.f ? o.w : 0.f;       \
                if (rowOk)                                                     \
                    *(float4*)&out[orow * D_DIM + ct * 16 + quad * 4] = o;     \
            }                                                                  \
        }                                                                      \
    }

__global__ __launch_bounds__(NTHR, 4)
void ctx_encoder(const int* __restrict__ nodes,
                 const float* __restrict__ c2e,
                 const float* __restrict__ w1,
                 const float* __restrict__ b1,
                 const float* __restrict__ w2,
                 const float* __restrict__ b2,
                 float* __restrict__ out,
                 int N) {
    __shared__ unsigned short sW1[D_DIM * 128];   // 32 KB
    __shared__ unsigned short sW2[D_DIM * 128];   // 32 KB
    __shared__ unsigned short sX [MT    * 128];   // 16 KB shared A/h buffer -> 80 KB

    const int t    = threadIdx.x;
    const int lane = t & 63;
    const int wave = t >> 6;       // 0..7
    const int pair = wave >> 1;    // m-tile 0..3 (16 node rows)
    const int half = wave & 1;     // ct-group
    const int cl   = lane & 15;
    const int quad = lane >> 4;

    // gather role: thread t fetches contiguous 16B slices of row (t>>3)
    const int grow0 = t >> 3;      // row within tile, 0..63
    const int gc    = t & 7;       // 16B chunk position (8 lanes = 128B runs)

    stage_w(w1, sW1, t);
    stage_w(w2, sW2, t);

    // biases, vectorized per (c, quad): j = ct*16 + quad*4 + r
    float4 bias1[4], bias2[4];
    #pragma unroll
    for (int c = 0; c < 4; ++c) {
        const int ct = half * 4 + c;
        bias1[c] = ((const float4*)b1)[ct * 4 + quad];
        bias2[c] = ((const float4*)b2)[ct * 4 + quad];
    }

    const int nTiles = (N + MT - 1) / MT;
    const int lastT  = nTiles - 1;

    auto loadIdx = [&](int tt) -> int {
        tt = tt < lastT ? tt : lastT;
        int r = tt * MT + grow0;
        r = r < N ? r : N - 1;
        return nodes[r];
    };

    int tl = blockIdx.x;

    // ---- prologue: two tiles of gather in flight, all in named registers ----
    float4 gA0, gA1, gA2, gA3, gB0, gB1, gB2, gB3;
    int idxA = loadIdx(tl);
    GATHER(idxA, gA0, gA1, gA2, gA3);
    int idxB = loadIdx(tl + NBLOCKS);
    GATHER(idxB, gB0, gB1, gB2, gB3);
    int idxN0 = loadIdx(tl + 2 * NBLOCKS);
    int idxN1 = loadIdx(tl + 3 * NBLOCKS);

    __syncthreads();   // weights staged

    for (; tl < nTiles; tl += 2 * NBLOCKS) {
        BODY(tl, gA0, gA1, gA2, gA3, idxN0);
        if (tl + NBLOCKS < nTiles) {          // block-uniform condition
            BODY(tl + NBLOCKS, gB0, gB1, gB2, gB3, idxN1);
        }
    }
}

extern "C" void kernel_launch(void* const* d_in, const int* in_sizes, int n_in,
                              void* d_out, int out_size, void* d_ws, size_t ws_size,
                              hipStream_t stream) {
    const int*   nodes = (const int*)d_in[0];
    const float* c2e   = (const float*)d_in[1];
    const float* w1    = (const float*)d_in[2];
    const float* b1    = (const float*)d_in[3];
    const float* w2    = (const float*)d_in[4];
    const float* b2    = (const float*)d_in[5];
    float* out = (float*)d_out;
    const int N = in_sizes[0];

    ctx_encoder<<<dim3(NBLOCKS), dim3(NTHR), 0, stream>>>(nodes, c2e, w1, b1, w2, b2, out, N);
}

// Round 9
// 202.069 us; speedup vs baseline: 1.0784x; 1.0080x over previous
//
#include <hip/hip_runtime.h>
#include <hip/hip_bf16.h>

#define D_DIM   128
#define MT      64        // node rows per block-iteration (3125 tiles exactly)
#define NBLOCKS 512       // persistent: 2 blocks/CU x 256 CUs
#define NTHR    512

typedef __attribute__((ext_vector_type(8))) short bf16x8;
typedef __attribute__((ext_vector_type(4))) float f32x4;

__device__ __forceinline__ unsigned short f2bf(float f) {
    return __builtin_bit_cast(unsigned short, __float2bfloat16(f));
}

// XOR-swizzled offset (in shorts) into a [rows][128] bf16 LDS tile.
// 16B chunks permuted per row: conflict-free ds_read_b128, zero padding.
__device__ __forceinline__ int sw_off(int row, int col) {
    return row * 128 + ((((col >> 3) ^ (row & 15)) << 3) | (col & 7));
}

// stage a 128x128 fp32 matrix into swizzled bf16 LDS; coalesced global reads
__device__ __forceinline__ void stage_w(const float* __restrict__ w,
                                        unsigned short* __restrict__ sW, int t) {
    #pragma unroll
    for (int i = 0; i < 8; ++i) {                 // 4096 float4 / 512 threads
        const int idx4 = i * NTHR + t;
        const float4 v = ((const float4*)w)[idx4];
        const int row = idx4 >> 5;                // 32 float4 per row
        const int c4  = (idx4 & 31) * 4;
        ushort4 b;
        b.x = f2bf(v.x); b.y = f2bf(v.y); b.z = f2bf(v.z); b.w = f2bf(v.w);
        *(ushort4*)&sW[sw_off(row, c4)] = b;
    }
}

// gather one embedding row slice into 4 named float4 registers
#define GATHER(IDX, G0, G1, G2, G3)                                    \
    {                                                                  \
        const float* rp_ = c2e + (size_t)(IDX) * D_DIM + gc * 4;       \
        G0 = *(const float4*)(rp_);                                    \
        G1 = *(const float4*)(rp_ + 32);                               \
        G2 = *(const float4*)(rp_ + 64);                               \
        G3 = *(const float4*)(rp_ + 96);                               \
    }

// one tile: stage gathered regs -> LDS, layer1, layer2, store; refill G with
// tile (TCUR + 2*NBLOCKS) and advance its index register.
#define BODY(TCUR, G0, G1, G2, G3, IDXREF)                                     \
    {                                                                          \
        /* s1: gathered rows -> bf16 -> sX (swizzled) */                       \
        {                                                                      \
            ushort4 b_;                                                        \
            b_.x = f2bf(G0.x); b_.y = f2bf(G0.y);                              \
            b_.z = f2bf(G0.z); b_.w = f2bf(G0.w);                              \
            *(ushort4*)&sX[sw_off(grow0, gc * 4)] = b_;                        \
            b_.x = f2bf(G1.x); b_.y = f2bf(G1.y);                              \
            b_.z = f2bf(G1.z); b_.w = f2bf(G1.w);                              \
            *(ushort4*)&sX[sw_off(grow0, gc * 4 + 32)] = b_;                   \
            b_.x = f2bf(G2.x); b_.y = f2bf(G2.y);                              \
            b_.z = f2bf(G2.z); b_.w = f2bf(G2.w);                              \
            *(ushort4*)&sX[sw_off(grow0, gc * 4 + 64)] = b_;                   \
            b_.x = f2bf(G3.x); b_.y = f2bf(G3.y);                              \
            b_.z = f2bf(G3.z); b_.w = f2bf(G3.w);                              \
            *(ushort4*)&sX[sw_off(grow0, gc * 4 + 96)] = b_;                   \
        }                                                                      \
        __syncthreads(); /* B1: sX(A) ready */                                 \
        /* s2: x-fragments from LDS */                                         \
        bf16x8 xF0 = *(const bf16x8*)&sX[sw_off(pair * 16 + cl, quad * 8)];    \
        bf16x8 xF1 = *(const bf16x8*)&sX[sw_off(pair * 16 + cl, 32 + quad * 8)];\
        bf16x8 xF2 = *(const bf16x8*)&sX[sw_off(pair * 16 + cl, 64 + quad * 8)];\
        bf16x8 xF3 = *(const bf16x8*)&sX[sw_off(pair * 16 + cl, 96 + quad * 8)];\
        /* s3: refill gather (distance 2) + advance index pipeline */          \
        GATHER(IDXREF, G0, G1, G2, G3);                                        \
        IDXREF = loadIdx((TCUR) + 4 * NBLOCKS);                                \
        __syncthreads(); /* B2: xF reads done; sX reusable for h */            \
        /* s4: layer 1, operand-swapped: lane reg axis = feature j */          \
        _Pragma("unroll")                                                      \
        for (int c = 0; c < 4; ++c) {                                          \
            const int ct = half * 4 + c;                                       \
            bf16x8 w0 = *(const bf16x8*)&sW1[sw_off(ct * 16 + cl, quad * 8)];  \
            bf16x8 w1_ = *(const bf16x8*)&sW1[sw_off(ct * 16 + cl, 32 + quad * 8)];\
            bf16x8 w2_ = *(const bf16x8*)&sW1[sw_off(ct * 16 + cl, 64 + quad * 8)];\
            bf16x8 w3_ = *(const bf16x8*)&sW1[sw_off(ct * 16 + cl, 96 + quad * 8)];\
            f32x4 acc = {0.f, 0.f, 0.f, 0.f};                                  \
            acc = __builtin_amdgcn_mfma_f32_16x16x32_bf16(w0, xF0, acc, 0, 0, 0);\
            acc = __builtin_amdgcn_mfma_f32_16x16x32_bf16(w1_, xF1, acc, 0, 0, 0);\
            acc = __builtin_amdgcn_mfma_f32_16x16x32_bf16(w2_, xF2, acc, 0, 0, 0);\
            acc = __builtin_amdgcn_mfma_f32_16x16x32_bf16(w3_, xF3, acc, 0, 0, 0);\
            ushort4 hw;                                                        \
            float h0 = acc[0] + bias1[c].x;  h0 = h0 > 0.f ? h0 : 0.f;         \
            float h1 = acc[1] + bias1[c].y;  h1 = h1 > 0.f ? h1 : 0.f;         \
            float h2 = acc[2] + bias1[c].z;  h2 = h2 > 0.f ? h2 : 0.f;         \
            float h3 = acc[3] + bias1[c].w;  h3 = h3 > 0.f ? h3 : 0.f;         \
            hw.x = f2bf(h0); hw.y = f2bf(h1); hw.z = f2bf(h2); hw.w = f2bf(h3);\
            *(ushort4*)&sX[sw_off(pair * 16 + cl, ct * 16 + quad * 4)] = hw;   \
        }                                                                      \
        __syncthreads(); /* B3: sX(h) ready */                                 \
        /* s5: h-fragments */                                                  \
        bf16x8 hF0 = *(const bf16x8*)&sX[sw_off(pair * 16 + cl, quad * 8)];    \
        bf16x8 hF1 = *(const bf16x8*)&sX[sw_off(pair * 16 + cl, 32 + quad * 8)];\
        bf16x8 hF2 = *(const bf16x8*)&sX[sw_off(pair * 16 + cl, 64 + quad * 8)];\
        bf16x8 hF3 = *(const bf16x8*)&sX[sw_off(pair * 16 + cl, 96 + quad * 8)];\
        __syncthreads(); /* B4: hF reads done; sX free for next gather */      \
        /* s6: layer 2, operand-swapped + float4 stores */                     \
        {                                                                      \
            const size_t orow = (size_t)(TCUR) * MT + pair * 16 + cl;          \
            const bool rowOk = orow < (size_t)N;                               \
            _Pragma("unroll")                                                  \
            for (int c = 0; c < 4; ++c) {                                      \
                const int ct = half * 4 + c;                                   \
                bf16x8 w0 = *(const bf16x8*)&sW2[sw_off(ct * 16 + cl, quad * 8)];\
                bf16x8 w1_ = *(const bf16x8*)&sW2[sw_off(ct * 16 + cl, 32 + quad * 8)];\
                bf16x8 w2_ = *(const bf16x8*)&sW2[sw_off(ct * 16 + cl, 64 + quad * 8)];\
                bf16x8 w3_ = *(const bf16x8*)&sW2[sw_off(ct * 16 + cl, 96 + quad * 8)];\
                f32x4 acc = {0.f, 0.f, 0.f, 0.f};                              \
                acc = __builtin_amdgcn_mfma_f32_16x16x32_bf16(w0, hF0, acc, 0, 0, 0);\
                acc = __builtin_amdgcn_mfma_f32_16x16x32_bf16(w1_, hF1, acc, 0, 0, 0);\
                acc = __builtin_amdgcn_mfma_f32_16x16x32_bf16(w2_, hF2, acc, 0, 0, 0);\
                acc = __builtin_amdgcn_mfma_f32_16x16x32_bf16(w3_, hF3, acc, 0, 0, 0);\
                float4 o;                                                      \
                o.x = acc[0] + bias2[c].x;  o.x = o.x > 0.f ? o.x : 0.f;       \
                o.y = acc[1] + bias2[c].y;  o.y = o.y > 0.f ? o.y : 0.f;       \
                o.z = acc[2] + bias2[c].z;  o.z = o.z > 0.f ? o.z : 0.f;       \
                o.w = acc[3] + bias2[c].w;  o.w = o.w > 0.f ? o.w : 0.f;       \
                if (rowOk)                                                     \
                    *(float4*)&out[orow * D_DIM + ct * 16 + quad * 4] = o;     \
            }                                                                  \
        }                                                                      \
    }

// LDS caps occupancy at 2 blocks/CU = 4 waves/EU, so pin the register
// allocator to that occupancy: 128-VGPR budget, no scratch spill.
// (Plain __launch_bounds__(512,4) left the allocator at the 8-wave/64-VGPR
// target and spilled ~60 MB/launch to scratch — R4..R8 evidence.)
__global__ __launch_bounds__(NTHR)
__attribute__((amdgpu_waves_per_eu(4, 4)))
void ctx_encoder(const int* __restrict__ nodes,
                 const float* __restrict__ c2e,
                 const float* __restrict__ w1,
                 const float* __restrict__ b1,
                 const float* __restrict__ w2,
                 const float* __restrict__ b2,
                 float* __restrict__ out,
                 int N) {
    __shared__ unsigned short sW1[D_DIM * 128];   // 32 KB
    __shared__ unsigned short sW2[D_DIM * 128];   // 32 KB
    __shared__ unsigned short sX [MT    * 128];   // 16 KB shared A/h buffer -> 80 KB

    const int t    = threadIdx.x;
    const int lane = t & 63;
    const int wave = t >> 6;       // 0..7
    const int pair = wave >> 1;    // m-tile 0..3 (16 node rows)
    const int half = wave & 1;     // ct-group
    const int cl   = lane & 15;
    const int quad = lane >> 4;

    // gather role: thread t fetches contiguous 16B slices of row (t>>3)
    const int grow0 = t >> 3;      // row within tile, 0..63
    const int gc    = t & 7;       // 16B chunk position (8 lanes = 128B runs)

    stage_w(w1, sW1, t);
    stage_w(w2, sW2, t);

    // biases, vectorized per (c, quad): j = ct*16 + quad*4 + r
    float4 bias1[4], bias2[4];
    #pragma unroll
    for (int c = 0; c < 4; ++c) {
        const int ct = half * 4 + c;
        bias1[c] = ((const float4*)b1)[ct * 4 + quad];
        bias2[c] = ((const float4*)b2)[ct * 4 + quad];
    }

    const int nTiles = (N + MT - 1) / MT;
    const int lastT  = nTiles - 1;

    auto loadIdx = [&](int tt) -> int {
        tt = tt < lastT ? tt : lastT;
        int r = tt * MT + grow0;
        r = r < N ? r : N - 1;
        return nodes[r];
    };

    int tl = blockIdx.x;

    // ---- prologue: two tiles of gather in flight, all in named registers ----
    float4 gA0, gA1, gA2, gA3, gB0, gB1, gB2, gB3;
    int idxA = loadIdx(tl);
    GATHER(idxA, gA0, gA1, gA2, gA3);
    int idxB = loadIdx(tl + NBLOCKS);
    GATHER(idxB, gB0, gB1, gB2, gB3);
    int idxN0 = loadIdx(tl + 2 * NBLOCKS);
    int idxN1 = loadIdx(tl + 3 * NBLOCKS);

    __syncthreads();   // weights staged

    for (; tl < nTiles; tl += 2 * NBLOCKS) {
        BODY(tl, gA0, gA1, gA2, gA3, idxN0);
        if (tl + NBLOCKS < nTiles) {          // block-uniform condition
            BODY(tl + NBLOCKS, gB0, gB1, gB2, gB3, idxN1);
        }
    }
}

extern "C" void kernel_launch(void* const* d_in, const int* in_sizes, int n_in,
                              void* d_out, int out_size, void* d_ws, size_t ws_size,
                              hipStream_t stream) {
    const int*   nodes = (const int*)d_in[0];
    const float* c2e   = (const float*)d_in[1];
    const float* w1    = (const float*)d_in[2];
    const float* b1    = (const float*)d_in[3];
    const float* w2    = (const float*)d_in[4];
    const float* b2    = (const float*)d_in[5];
    float* out = (float*)d_out;
    const int N = in_sizes[0];

    ctx_encoder<<<dim3(NBLOCKS), dim3(NTHR), 0, stream>>>(nodes, c2e, w1, b1, w2, b2, out, N);
}

// Round 10
// 168.077 us; speedup vs baseline: 1.2965x; 1.2022x over previous
//
#include <hip/hip_runtime.h>
#include <hip/hip_bf16.h>

#define D_DIM   128
#define MT      64        // node rows per block-iteration (3125 tiles exactly)
#define NBLOCKS 512       // persistent: 2 blocks/CU x 256 CUs
#define NTHR    512

typedef __attribute__((ext_vector_type(8))) short bf16x8;
typedef __attribute__((ext_vector_type(4))) float f32x4;

__device__ __forceinline__ unsigned short f2bf(float f) {
    return __builtin_bit_cast(unsigned short, __float2bfloat16(f));
}

// XOR-swizzled offset (in shorts) into a [rows][128] bf16 LDS tile.
// 16B chunks permuted per row: conflict-free ds_read_b128, zero padding.
__device__ __forceinline__ int sw_off(int row, int col) {
    return row * 128 + ((((col >> 3) ^ (row & 15)) << 3) | (col & 7));
}

// stage a 128x128 fp32 matrix into swizzled bf16 LDS; coalesced global reads
__device__ __forceinline__ void stage_w(const float* __restrict__ w,
                                        unsigned short* __restrict__ sW, int t) {
    #pragma unroll
    for (int i = 0; i < 8; ++i) {                 // 4096 float4 / 512 threads
        const int idx4 = i * NTHR + t;
        const float4 v = ((const float4*)w)[idx4];
        const int row = idx4 >> 5;                // 32 float4 per row
        const int c4  = (idx4 & 31) * 4;
        ushort4 b;
        b.x = f2bf(v.x); b.y = f2bf(v.y); b.z = f2bf(v.z); b.w = f2bf(v.w);
        *(ushort4*)&sW[sw_off(row, c4)] = b;
    }
}

// gather one embedding row slice into 4 named float4 registers.
// Per instruction: 8 lanes x 16B cover a contiguous 128B run of one row.
#define GATHER(IDX, G0, G1, G2, G3)                                    \
    {                                                                  \
        const float* rp_ = c2e + (size_t)(IDX) * D_DIM + gc * 4;       \
        G0 = *(const float4*)(rp_);                                    \
        G1 = *(const float4*)(rp_ + 32);                               \
        G2 = *(const float4*)(rp_ + 64);                               \
        G3 = *(const float4*)(rp_ + 96);                               \
    }

// Register budget note: compiler pins VGPR=64 regardless of launch bounds /
// waves_per_eu (R8/R9 evidence). Steady-state live regs MUST fit 64:
// single gather buffer (16) + idx (1); biases read per-use from global
// (b1/b2 = 512B each, L1-resident forever). Two register gather buffers +
// register biases (R6-R9) = 64 persistent regs -> ~130 MB scratch spill.
__global__ __launch_bounds__(NTHR, 4)
void ctx_encoder(const int* __restrict__ nodes,
                 const float* __restrict__ c2e,
                 const float* __restrict__ w1,
                 const float* __restrict__ b1,
                 const float* __restrict__ w2,
                 const float* __restrict__ b2,
                 float* __restrict__ out,
                 int N) {
    __shared__ unsigned short sW1[D_DIM * 128];   // 32 KB
    __shared__ unsigned short sW2[D_DIM * 128];   // 32 KB
    __shared__ unsigned short sX [MT    * 128];   // 16 KB -> 80 KB, 2 blocks/CU

    const int t    = threadIdx.x;
    const int lane = t & 63;
    const int wave = t >> 6;       // 0..7
    const int pair = wave >> 1;    // m-tile 0..3 (16 node rows)
    const int half = wave & 1;     // ct-group
    const int cl   = lane & 15;
    const int quad = lane >> 4;

    // gather role: thread t fetches contiguous 16B slices of row (t>>3)
    const int grow0 = t >> 3;      // row within tile, 0..63
    const int gc    = t & 7;       // 16B chunk position (8 lanes = 128B runs)

    stage_w(w1, sW1, t);
    stage_w(w2, sW2, t);

    const int nTiles = (N + MT - 1) / MT;
    const int lastT  = nTiles - 1;

    auto loadIdx = [&](int tt) -> int {
        tt = tt < lastT ? tt : lastT;
        int r = tt * MT + grow0;
        r = r < N ? r : N - 1;
        return nodes[r];
    };

    int tl = blockIdx.x;

    // ---- prologue: one tile of gather in flight, next index prefetched ----
    float4 G0, G1, G2, G3;
    int idx0 = loadIdx(tl);
    GATHER(idx0, G0, G1, G2, G3);
    int idx_nxt = loadIdx(tl + NBLOCKS);

    __syncthreads();   // weights staged

    for (; tl < nTiles; tl += NBLOCKS) {
        // ---- s1: gathered rows -> bf16 -> sX (swizzled) ----
        {
            ushort4 b_;
            b_.x = f2bf(G0.x); b_.y = f2bf(G0.y);
            b_.z = f2bf(G0.z); b_.w = f2bf(G0.w);
            *(ushort4*)&sX[sw_off(grow0, gc * 4)] = b_;
            b_.x = f2bf(G1.x); b_.y = f2bf(G1.y);
            b_.z = f2bf(G1.z); b_.w = f2bf(G1.w);
            *(ushort4*)&sX[sw_off(grow0, gc * 4 + 32)] = b_;
            b_.x = f2bf(G2.x); b_.y = f2bf(G2.y);
            b_.z = f2bf(G2.z); b_.w = f2bf(G2.w);
            *(ushort4*)&sX[sw_off(grow0, gc * 4 + 64)] = b_;
            b_.x = f2bf(G3.x); b_.y = f2bf(G3.y);
            b_.z = f2bf(G3.z); b_.w = f2bf(G3.w);
            *(ushort4*)&sX[sw_off(grow0, gc * 4 + 96)] = b_;
        }
        __syncthreads();   // B1: sX(A) ready

        // ---- s2: x-fragments from LDS (lane: x[node=pair*16+cl][k]) ----
        bf16x8 xF0 = *(const bf16x8*)&sX[sw_off(pair * 16 + cl, quad * 8)];
        bf16x8 xF1 = *(const bf16x8*)&sX[sw_off(pair * 16 + cl, 32 + quad * 8)];
        bf16x8 xF2 = *(const bf16x8*)&sX[sw_off(pair * 16 + cl, 64 + quad * 8)];
        bf16x8 xF3 = *(const bf16x8*)&sX[sw_off(pair * 16 + cl, 96 + quad * 8)];

        // ---- s3: prefetch next tile's gather (hides under MFMA phases) ----
        GATHER(idx_nxt, G0, G1, G2, G3);
        idx_nxt = loadIdx(tl + 2 * NBLOCKS);
        __syncthreads();   // B2: xF reads done; sX reusable for h

        // ---- s4: layer 1, operand-swapped (lane reg axis = feature j) ----
        #pragma unroll
        for (int c = 0; c < 4; ++c) {
            const int ct = half * 4 + c;
            bf16x8 w0  = *(const bf16x8*)&sW1[sw_off(ct * 16 + cl, quad * 8)];
            bf16x8 w1_ = *(const bf16x8*)&sW1[sw_off(ct * 16 + cl, 32 + quad * 8)];
            bf16x8 w2_ = *(const bf16x8*)&sW1[sw_off(ct * 16 + cl, 64 + quad * 8)];
            bf16x8 w3_ = *(const bf16x8*)&sW1[sw_off(ct * 16 + cl, 96 + quad * 8)];
            f32x4 acc = {0.f, 0.f, 0.f, 0.f};
            acc = __builtin_amdgcn_mfma_f32_16x16x32_bf16(w0,  xF0, acc, 0, 0, 0);
            acc = __builtin_amdgcn_mfma_f32_16x16x32_bf16(w1_, xF1, acc, 0, 0, 0);
            acc = __builtin_amdgcn_mfma_f32_16x16x32_bf16(w2_, xF2, acc, 0, 0, 0);
            acc = __builtin_amdgcn_mfma_f32_16x16x32_bf16(w3_, xF3, acc, 0, 0, 0);
            const float4 bb = *(const float4*)&b1[ct * 16 + quad * 4];  // L1-hot
            ushort4 hw;
            float h0 = acc[0] + bb.x;  h0 = h0 > 0.f ? h0 : 0.f;
            float h1 = acc[1] + bb.y;  h1 = h1 > 0.f ? h1 : 0.f;
            float h2 = acc[2] + bb.z;  h2 = h2 > 0.f ? h2 : 0.f;
            float h3 = acc[3] + bb.w;  h3 = h3 > 0.f ? h3 : 0.f;
            hw.x = f2bf(h0); hw.y = f2bf(h1); hw.z = f2bf(h2); hw.w = f2bf(h3);
            *(ushort4*)&sX[sw_off(pair * 16 + cl, ct * 16 + quad * 4)] = hw;
        }
        __syncthreads();   // B3: sX(h) ready

        // ---- s5: h-fragments ----
        bf16x8 hF0 = *(const bf16x8*)&sX[sw_off(pair * 16 + cl, quad * 8)];
        bf16x8 hF1 = *(const bf16x8*)&sX[sw_off(pair * 16 + cl, 32 + quad * 8)];
        bf16x8 hF2 = *(const bf16x8*)&sX[sw_off(pair * 16 + cl, 64 + quad * 8)];
        bf16x8 hF3 = *(const bf16x8*)&sX[sw_off(pair * 16 + cl, 96 + quad * 8)];
        __syncthreads();   // B4: hF reads done; sX free for next gather

        // ---- s6: layer 2, operand-swapped + float4 stores ----
        const size_t orow = (size_t)tl * MT + pair * 16 + cl;
        const bool rowOk = orow < (size_t)N;
        #pragma unroll
        for (int c = 0; c < 4; ++c) {
            const int ct = half * 4 + c;
            bf16x8 w0  = *(const bf16x8*)&sW2[sw_off(ct * 16 + cl, quad * 8)];
            bf16x8 w1_ = *(const bf16x8*)&sW2[sw_off(ct * 16 + cl, 32 + quad * 8)];
            bf16x8 w2_ = *(const bf16x8*)&sW2[sw_off(ct * 16 + cl, 64 + quad * 8)];
            bf16x8 w3_ = *(const bf16x8*)&sW2[sw_off(ct * 16 + cl, 96 + quad * 8)];
            f32x4 acc = {0.f, 0.f, 0.f, 0.f};
            acc = __builtin_amdgcn_mfma_f32_16x16x32_bf16(w0,  hF0, acc, 0, 0, 0);
            acc = __builtin_amdgcn_mfma_f32_16x16x32_bf16(w1_, hF1, acc, 0, 0, 0);
            acc = __builtin_amdgcn_mfma_f32_16x16x32_bf16(w2_, hF2, acc, 0, 0, 0);
            acc = __builtin_amdgcn_mfma_f32_16x16x32_bf16(w3_, hF3, acc, 0, 0, 0);
            const float4 bb = *(const float4*)&b2[ct * 16 + quad * 4];  // L1-hot
            float4 o;
            o.x = acc[0] + bb.x;  o.x = o.x > 0.f ? o.x : 0.f;
            o.y = acc[1] + bb.y;  o.y = o.y > 0.f ? o.y : 0.f;
            o.z = acc[2] + bb.z;  o.z = o.z > 0.f ? o.z : 0.f;
            o.w = acc[3] + bb.w;  o.w = o.w > 0.f ? o.w : 0.f;
            if (rowOk)
                *(float4*)&out[orow * D_DIM + ct * 16 + quad * 4] = o;
        }
    }
}

extern "C" void kernel_launch(void* const* d_in, const int* in_sizes, int n_in,
                              void* d_out, int out_size, void* d_ws, size_t ws_size,
                              hipStream_t stream) {
    const int*   nodes = (const int*)d_in[0];
    const float* c2e   = (const float*)d_in[1];
    const float* w1    = (const float*)d_in[2];
    const float* b1    = (const float*)d_in[3];
    const float* w2    = (const float*)d_in[4];
    const float* b2    = (const float*)d_in[5];
    float* out = (float*)d_out;
    const int N = in_sizes[0];

    ctx_encoder<<<dim3(NBLOCKS), dim3(NTHR), 0, stream>>>(nodes, c2e, w1, b1, w2, b2, out, N);
}